// Round 1
// baseline (17.062 us; speedup 1.0000x reference)
//
#include <hip/hip_runtime.h>

#define NQ 16
#define DIM 65536          // 2^16
#define BPB 8              // blocks per batch row
#define CHUNK (DIM / BPB)  // 8192 floats per block

// out[b, i] = prod_q p_q[bit_q(i)]  (product state -> separable probabilities)
// Factor: out[i] = low8[i & 255] * high8[i >> 8]
__global__ __launch_bounds__(256) void qprob_kernel(
    const float* __restrict__ emb,   // [B, 768] (only first 48 cols used)
    const float* __restrict__ rot,   // [16, 3]
    float* __restrict__ out)         // [B, 65536]
{
    __shared__ float p0s[NQ], p1s[NQ];
    __shared__ float low8[256];
    __shared__ float high8[256];

    const int b = blockIdx.x / BPB;
    const int j = blockIdx.x % BPB;
    const int t = threadIdx.x;

    // Per-qubit column-0 probabilities. Rz is a pure phase -> only rx, ry matter.
    if (t < NQ) {
        const float rx = emb[b * 768 + t * 3 + 0] + rot[t * 3 + 0];
        const float ry = emb[b * 768 + t * 3 + 1] + rot[t * 3 + 1];
        float sx, cx, sy, cy;
        sincosf(rx * 0.5f, &sx, &cx);
        sincosf(ry * 0.5f, &sy, &cy);
        const float cx2 = cx * cx, sx2 = sx * sx;
        const float cy2 = cy * cy, sy2 = sy * sy;
        p0s[t] = cx2 * cy2 + sx2 * sy2;   // |amp(bit=0)|^2
        p1s[t] = cx2 * sy2 + sx2 * cy2;   // |amp(bit=1)|^2
    }
    __syncthreads();

    // Build 256-entry product tables for low 8 bits and high 8 bits.
    float lo = 1.0f, hi = 1.0f;
#pragma unroll
    for (int q = 0; q < 8; ++q) {
        lo *= ((t >> q) & 1) ? p1s[q]     : p0s[q];
        hi *= ((t >> q) & 1) ? p1s[q + 8] : p0s[q + 8];
    }
    low8[t] = lo;
    high8[t] = hi;
    __syncthreads();

    // Each thread's 4 consecutive low-bit values are fixed across iterations.
    const int l = (4 * t) & 255;
    const float l0 = low8[l + 0];
    const float l1 = low8[l + 1];
    const float l2 = low8[l + 2];
    const float l3 = low8[l + 3];

    float4* outrow = (float4*)(out + (size_t)b * DIM + (size_t)j * CHUNK);
#pragma unroll
    for (int k = 0; k < CHUNK / 1024; ++k) {   // 8 float4 stores/thread
        const int e4 = k * 256 + t;            // float4 index within chunk
        const int i0 = e4 * 4;                 // element index within chunk
        // high index is wave-uniform -> LDS broadcast (conflict-free)
        const float h = high8[(j * CHUNK + i0) >> 8];
        outrow[e4] = make_float4(l0 * h, l1 * h, l2 * h, l3 * h);
    }
}

extern "C" void kernel_launch(void* const* d_in, const int* in_sizes, int n_in,
                              void* d_out, int out_size, void* d_ws, size_t ws_size,
                              hipStream_t stream) {
    const float* emb = (const float*)d_in[0];  // [B, 768] float32
    const float* rot = (const float*)d_in[1];  // [16, 3]  float32
    float* out = (float*)d_out;                // [B, 65536] float32

    const int B = in_sizes[0] / 768;           // 256
    dim3 grid(B * BPB), block(256);
    qprob_kernel<<<grid, block, 0, stream>>>(emb, rot, out);
}

// Round 3
// 16.660 us; speedup vs baseline: 1.0241x; 1.0241x over previous
//
#include <hip/hip_runtime.h>

#define NQ 16
#define DIM 65536          // 2^16
#define BPB 8              // blocks per batch row
#define CHUNK (DIM / BPB)  // 8192 floats per block

typedef float f32x4 __attribute__((ext_vector_type(4)));

// out[b, i] = prod_q p_q[bit_q(i)]  (product state -> separable probabilities)
// Factor: out[i] = low8[i & 255] * high8[i >> 8]
__global__ __launch_bounds__(256) void qprob_kernel(
    const float* __restrict__ emb,   // [B, 768] (only first 48 cols used)
    const float* __restrict__ rot,   // [16, 3]
    float* __restrict__ out)         // [B, 65536]
{
    __shared__ float p0s[NQ], p1s[NQ];
    __shared__ float low8[256];
    __shared__ float high8[256];

    const int b = blockIdx.x / BPB;
    const int j = blockIdx.x % BPB;
    const int t = threadIdx.x;

    // Per-qubit column-0 probabilities. Rz is a pure phase -> only rx, ry matter.
    if (t < NQ) {
        const float rx = emb[b * 768 + t * 3 + 0] + rot[t * 3 + 0];
        const float ry = emb[b * 768 + t * 3 + 1] + rot[t * 3 + 1];
        float sx, cx, sy, cy;
        sincosf(rx * 0.5f, &sx, &cx);
        sincosf(ry * 0.5f, &sy, &cy);
        const float cx2 = cx * cx, sx2 = sx * sx;
        const float cy2 = cy * cy, sy2 = sy * sy;
        p0s[t] = cx2 * cy2 + sx2 * sy2;   // |amp(bit=0)|^2
        p1s[t] = cx2 * sy2 + sx2 * cy2;   // |amp(bit=1)|^2
    }
    __syncthreads();

    // Build 256-entry product tables for low 8 bits and high 8 bits.
    float lo = 1.0f, hi = 1.0f;
#pragma unroll
    for (int q = 0; q < 8; ++q) {
        lo *= ((t >> q) & 1) ? p1s[q]     : p0s[q];
        hi *= ((t >> q) & 1) ? p1s[q + 8] : p0s[q + 8];
    }
    low8[t] = lo;
    high8[t] = hi;
    __syncthreads();

    // Low-bit factors for this thread's 4 consecutive elements (fixed over k).
    const int l = (4 * t) & 255;
    const f32x4 lv = *(const f32x4*)&low8[l];

    // Hoist ALL high-bit factors (wave-uniform LDS broadcasts) before storing,
    // so the 8 stores below are fully independent back-to-back.
    const int hb = j * (CHUNK >> 8) + (t >> 6);   // high index at k=0
    float h[CHUNK / 1024];
#pragma unroll
    for (int k = 0; k < CHUNK / 1024; ++k)
        h[k] = high8[hb + 4 * k];                 // +4 high slots per k step

    f32x4* outrow = (f32x4*)(out + (size_t)b * DIM + (size_t)j * CHUNK);
#pragma unroll
    for (int k = 0; k < CHUNK / 1024; ++k) {      // 8 independent float4 nt-stores
        const f32x4 v = lv * h[k];
        __builtin_nontemporal_store(v, &outrow[k * 256 + t]);
    }
}

extern "C" void kernel_launch(void* const* d_in, const int* in_sizes, int n_in,
                              void* d_out, int out_size, void* d_ws, size_t ws_size,
                              hipStream_t stream) {
    const float* emb = (const float*)d_in[0];  // [B, 768] float32
    const float* rot = (const float*)d_in[1];  // [16, 3]  float32
    float* out = (float*)d_out;                // [B, 65536] float32

    const int B = in_sizes[0] / 768;           // 256
    dim3 grid(B * BPB), block(256);
    qprob_kernel<<<grid, block, 0, stream>>>(emb, rot, out);
}